// Round 6
// baseline (630.157 us; speedup 1.0000x reference)
//
#include <hip/hip_runtime.h>
#include <math.h>

#define NS 64
#define INV2PI  0.15915494309189535f
#define NEGHL2E (-0.72134752044448170f)   // -0.5 * log2(e)

// Diagnostic: repeat the emit pass REP times (idempotent stores -> identical
// output). Makes the kernel outrank the ~255us poison fills in the top-5
// counter table AND yields the marginal cost of one pure emit pass.
#define REP 4

typedef __attribute__((ext_vector_type(4))) float vfloat4;  // native clang vector (nontemporal-store OK)

// P (3x21) flat row-major, exactly as in the reference.
__constant__ float c_P[63] = {
  0.8506508f, 0.0f, 0.5257311f, 0.809017f, 0.5f, 0.309017f, 0.5257311f,
  0.8506508f, 0.0f, 1.0f, 0.0f, 0.0f, 0.809017f, 0.5f, -0.309017f,
  0.8506508f, 0.0f, -0.5257311f, 0.309017f, 0.809017f, -0.5f,
  0.0f, 0.5257311f, -0.8506508f, 0.5f, 0.309017f, -0.809017f, 0.0f, 1.0f,
  0.0f, -0.5257311f, 0.8506508f, 0.0f, -0.309017f, 0.809017f, -0.5f, 0.0f,
  0.5257311f, 0.8506508f, -0.309017f, 0.809017f, 0.5f,
  0.309017f, 0.809017f, 0.5f, 0.5f, 0.309017f, 0.809017f, 0.5f, -0.309017f,
  0.809017f, 0.0f, 0.0f, 1.0f, -0.5f, 0.309017f, 0.809017f, -0.809017f,
  0.5f, 0.309017f, -0.809017f, 0.5f, -0.309017f
};

// Per-CHANNEL descriptor (768 entries): ((127+deg)<<23) | (src<<3) | phase.
struct DescTab768 { unsigned v[768]; };
static constexpr DescTab768 make_desc768() {
    DescTab768 t{};
    for (int c = 0; c < 768; ++c) {
        int deg, src, ph;
        if      (c < 48)  { deg = c / 3;               src = 21 + c % 3;        ph = 0; }
        else if (c < 96)  { int cc = c - 48;  deg = cc / 3;  src = 21 + cc % 3; ph = 1; }
        else if (c < 432) { int cc = c - 96;  deg = cc / 21; src = cc % 21;     ph = 0; }
        else              { int cc = c - 432; deg = cc / 21; src = cc % 21;     ph = 1; }
        t.v[c] = ((unsigned)(127 + deg) << 23) | ((unsigned)src << 3) | (unsigned)ph;
    }
    return t;
}
__constant__ DescTab768 cDesc = make_desc768();

struct Moments { float t_mean, t_var, r_var; };

__device__ inline Moments frustum_moments(float t0, float t1, float radius) {
    float mu  = 0.5f * (t0 + t1);
    float hw  = 0.5f * (t1 - t0);
    float mu2 = mu * mu, hw2 = hw * hw;
    float denom = 3.0f * mu2 + hw2;
    float inv_d = 1.0f / denom;
    float hw4 = hw2 * hw2;
    Moments m;
    m.t_mean = mu + 2.0f * mu * hw2 * inv_d;
    m.t_var  = hw2 * (1.0f / 3.0f)
             - (4.0f / 15.0f) * (hw4 * (12.0f * mu2 - hw2) * inv_d * inv_d);
    m.r_var  = radius * radius *
               (0.25f * mu2 + (5.0f / 12.0f) * hw2 - (4.0f / 15.0f) * hw4 * inv_d);
    return m;
}

// Emit 4 consecutive channels (one float4) from a per-lane descriptor quad.
__device__ inline void emit4(uint4 d, const char* __restrict__ rowXV, float* __restrict__ o) {
    vfloat4 v;
    {
        unsigned wd = d.x;
        float sf = __uint_as_float(wd & 0xFF800000u);                 // 2^deg
        float2 xv = *reinterpret_cast<const float2*>(rowXV + (wd & 0xF8u));
        float e  = __builtin_amdgcn_exp2f(xv.y * (sf * sf));          // exp(-0.5*var*4^deg)
        float ph = (float)(wd & 1u) * 0.25f;
        v.x = e * __builtin_amdgcn_sinf(__builtin_amdgcn_fractf(xv.x * sf + ph));
    }
    {
        unsigned wd = d.y;
        float sf = __uint_as_float(wd & 0xFF800000u);
        float2 xv = *reinterpret_cast<const float2*>(rowXV + (wd & 0xF8u));
        float e  = __builtin_amdgcn_exp2f(xv.y * (sf * sf));
        float ph = (float)(wd & 1u) * 0.25f;
        v.y = e * __builtin_amdgcn_sinf(__builtin_amdgcn_fractf(xv.x * sf + ph));
    }
    {
        unsigned wd = d.z;
        float sf = __uint_as_float(wd & 0xFF800000u);
        float2 xv = *reinterpret_cast<const float2*>(rowXV + (wd & 0xF8u));
        float e  = __builtin_amdgcn_exp2f(xv.y * (sf * sf));
        float ph = (float)(wd & 1u) * 0.25f;
        v.z = e * __builtin_amdgcn_sinf(__builtin_amdgcn_fractf(xv.x * sf + ph));
    }
    {
        unsigned wd = d.w;
        float sf = __uint_as_float(wd & 0xFF800000u);
        float2 xv = *reinterpret_cast<const float2*>(rowXV + (wd & 0xF8u));
        float e  = __builtin_amdgcn_exp2f(xv.y * (sf * sf));
        float ph = (float)(wd & 1u) * 0.25f;
        v.w = e * __builtin_amdgcn_sinf(__builtin_amdgcn_fractf(xv.x * sf + ph));
    }
    __builtin_nontemporal_store(v, reinterpret_cast<vfloat4*>(o));
}

__global__ __launch_bounds__(256, 4) void mipnerf_enc(
    const float* __restrict__ ray_o,
    const float* __restrict__ ray_d,
    const float* __restrict__ fgz,
    const float* __restrict__ bgz,
    const float* __restrict__ radii,
    float* __restrict__ out)
{
    const int n   = blockIdx.x;
    const int tid = threadIdx.x;

    __shared__ float sXV[NS * 50];
    __shared__ float sCore[NS * 11];
    __shared__ __align__(16) unsigned sD[768];

    const float ox = ray_o[3 * n + 0], oy = ray_o[3 * n + 1], oz = ray_o[3 * n + 2];
    const float dx = ray_d[3 * n + 0], dy = ray_d[3 * n + 1], dz = ray_d[3 * n + 2];
    const float rad = radii[n];
    const float dm = fmaxf(1e-8f, dx * dx + dy * dy + dz * dz);
    const float inv_dm = 1.0f / dm;

    if (tid < NS) {
        const int s = tid;
        { // ---- FG (diagonal covariance) ----
            float t0 = fgz[(NS + 1) * n + s];
            float t1 = fgz[(NS + 1) * n + s + 1];
            Moments mm = frustum_moments(t0, t1, rad);
            float d3[3] = {dx, dy, dz};
            float o3[3] = {ox, oy, oz};
            #pragma unroll
            for (int i = 0; i < 3; ++i) {
                float m  = o3[i] + d3[i] * mm.t_mean;
                float dd = d3[i] * d3[i];
                float cd = mm.t_var * dd + mm.r_var * (1.0f - dd * inv_dm);
                sXV[s * 50 + 2 * (21 + i) + 0] = m  * INV2PI;
                sXV[s * 50 + 2 * (21 + i) + 1] = cd * NEGHL2E;
            }
        }
        { // ---- BG core (full cov + contraction, closed form) ----
            float t0 = bgz[(NS + 1) * n + s];
            float t1 = bgz[(NS + 1) * n + s + 1];
            Moments mm = frustum_moments(t0, t1, rad);
            float x0 = ox + dx * mm.t_mean;
            float x1 = oy + dy * mm.t_mean;
            float x2 = oz + dz * mm.t_mean;
            float a  = mm.t_var - mm.r_var * inv_dm;   // C = a*ddT + rv*I
            float rv = mm.r_var;
            float rn2 = x0 * x0 + x1 * x1 + x2 * x2;
            float rn  = sqrtf(rn2);
            float nn  = rn + 1e-6f;
            float inn = 1.0f / nn;
            float g   = (2.0f * nn - 1.0f) * inn * inn;       // (2 - 1/n)/n
            float gp  = 2.0f * (1.0f - nn) * inn * inn * inn; // g'(n)
            float h   = gp / rn;                              // J = g*I + h*x*xT
            float xd  = x0 * dx + x1 * dy + x2 * dz;
            float hxd = h * xd;
            float u0 = g * dx + hxd * x0;                     // u = J d
            float u1 = g * dy + hxd * x1;
            float u2 = g * dz + hxd * x2;
            float w  = 2.0f * g * h + h * h * rn2;            // J^2 = g^2 I + w x xT
            float* cr = &sCore[s * 11];
            cr[0] = x0; cr[1] = x1; cr[2] = x2;
            cr[3] = u0; cr[4] = u1; cr[5] = u2;
            cr[6] = g;  cr[7] = a;  cr[8] = rv * g * g; cr[9] = rv * w;
        }
    } else {
        for (int e = tid - NS; e < 768; e += 256 - NS) sD[e] = cDesc.v[e];
    }
    __syncthreads();

    // ---- BG projections onto 21 basis columns (k wave-uniform, s = lane) ----
    #pragma unroll
    for (int j = 0; j < 6; ++j) {
        int i = tid + 256 * j;
        if (i < 21 * NS) {
            int k = i >> 6;        // wave-uniform
            int s = i & (NS - 1);  // = lane
            const float p0 = c_P[k], p1 = c_P[21 + k], p2 = c_P[42 + k];
            const float* cr = &sCore[s * 11];
            float x0 = cr[0], x1 = cr[1], x2 = cr[2];
            float u0 = cr[3], u1 = cr[4], u2 = cr[5];
            float g = cr[6], c1 = cr[7], c2 = cr[8], c3 = cr[9];
            float dpx = p0 * x0 + p1 * x1 + p2 * x2;
            float dpu = p0 * u0 + p1 * u1 + p2 * u2;
            float pp  = p0 * p0 + p1 * p1 + p2 * p2;
            float y   = g * dpx;
            float yv  = c1 * dpu * dpu + c2 * pp + c3 * dpx * dpx;
            sXV[s * 50 + 2 * k + 0] = y  * INV2PI;
            sXV[s * 50 + 2 * k + 1] = yv * NEGHL2E;
        }
    }
    __syncthreads();

    // ---- Emit (round-5 structure), repeated REP times for the counter probe.
    const int lane = tid & 63;
    const int w    = tid >> 6;     // wave id 0..3
    const uint4* sD4 = reinterpret_cast<const uint4*>(sD);
    const uint4 d0 = sD4[lane];        // channels   0 + lane*4 .. +3
    const uint4 d1 = sD4[64 + lane];   // channels 256 + lane*4 .. +3
    const uint4 d2 = sD4[128 + lane];  // channels 512 + lane*4 .. +3

    float* __restrict__ outp = out + (size_t)n * (NS * 768);

    for (int rep = 0; rep < REP; ++rep) {
        for (int ss = 0; ss < 16; ++ss) {
            const int s = w * 16 + ss;
            const char* rowXV = reinterpret_cast<const char*>(&sXV[s * 50]);
            float* orow = outp + s * 768 + lane * 4;
            emit4(d0, rowXV, orow);
            emit4(d1, rowXV, orow + 256);
            emit4(d2, rowXV, orow + 512);
        }
        // Keep every pass's stores live; prevent cross-pass store elimination.
        __asm volatile("" ::: "memory");
    }
}

extern "C" void kernel_launch(void* const* d_in, const int* in_sizes, int n_in,
                              void* d_out, int out_size, void* d_ws, size_t ws_size,
                              hipStream_t stream) {
    const float* ray_o = (const float*)d_in[0];
    const float* ray_d = (const float*)d_in[1];
    const float* fgz   = (const float*)d_in[2];
    const float* bgz   = (const float*)d_in[3];
    const float* radii = (const float*)d_in[4];
    float* out = (float*)d_out;
    const int N = in_sizes[0] / 3;   // 2048 rays
    mipnerf_enc<<<N, 256, 0, stream>>>(ray_o, ray_d, fgz, bgz, radii, out);
}

// Round 7
// 407.801 us; speedup vs baseline: 1.5453x; 1.5453x over previous
//
#include <hip/hip_runtime.h>
#include <math.h>

#define NS 64
#define INV2PI  0.15915494309189535f
#define NEGHL2E (-0.72134752044448170f)   // -0.5 * log2(e)

typedef __attribute__((ext_vector_type(4))) float vfloat4;  // native clang vector (nontemporal-store OK)

// P (3x21) flat row-major, exactly as in the reference.
__constant__ float c_P[63] = {
  0.8506508f, 0.0f, 0.5257311f, 0.809017f, 0.5f, 0.309017f, 0.5257311f,
  0.8506508f, 0.0f, 1.0f, 0.0f, 0.0f, 0.809017f, 0.5f, -0.309017f,
  0.8506508f, 0.0f, -0.5257311f, 0.309017f, 0.809017f, -0.5f,
  0.0f, 0.5257311f, -0.8506508f, 0.5f, 0.309017f, -0.809017f, 0.0f, 1.0f,
  0.0f, -0.5257311f, 0.8506508f, 0.0f, -0.309017f, 0.809017f, -0.5f, 0.0f,
  0.5257311f, 0.8506508f, -0.309017f, 0.809017f, 0.5f,
  0.309017f, 0.809017f, 0.5f, 0.5f, 0.309017f, 0.809017f, 0.5f, -0.309017f,
  0.809017f, 0.0f, 0.0f, 1.0f, -0.5f, 0.309017f, 0.809017f, -0.809017f,
  0.5f, 0.309017f, -0.809017f, 0.5f, -0.309017f
};

// Per-CHANNEL descriptor (768 entries): ((127+deg)<<23) | (src<<3) | phase.
struct DescTab768 { unsigned v[768]; };
static constexpr DescTab768 make_desc768() {
    DescTab768 t{};
    for (int c = 0; c < 768; ++c) {
        int deg, src, ph;
        if      (c < 48)  { deg = c / 3;               src = 21 + c % 3;        ph = 0; }
        else if (c < 96)  { int cc = c - 48;  deg = cc / 3;  src = 21 + cc % 3; ph = 1; }
        else if (c < 432) { int cc = c - 96;  deg = cc / 21; src = cc % 21;     ph = 0; }
        else              { int cc = c - 432; deg = cc / 21; src = cc % 21;     ph = 1; }
        t.v[c] = ((unsigned)(127 + deg) << 23) | ((unsigned)src << 3) | (unsigned)ph;
    }
    return t;
}
__constant__ DescTab768 cDesc = make_desc768();

struct Moments { float t_mean, t_var, r_var; };

__device__ inline Moments frustum_moments(float t0, float t1, float radius) {
    float mu  = 0.5f * (t0 + t1);
    float hw  = 0.5f * (t1 - t0);
    float mu2 = mu * mu, hw2 = hw * hw;
    float denom = 3.0f * mu2 + hw2;
    float inv_d = 1.0f / denom;
    float hw4 = hw2 * hw2;
    Moments m;
    m.t_mean = mu + 2.0f * mu * hw2 * inv_d;
    m.t_var  = hw2 * (1.0f / 3.0f)
             - (4.0f / 15.0f) * (hw4 * (12.0f * mu2 - hw2) * inv_d * inv_d);
    m.r_var  = radius * radius *
               (0.25f * mu2 + (5.0f / 12.0f) * hw2 - (4.0f / 15.0f) * hw4 * inv_d);
    return m;
}

// Emit 4 consecutive channels (one float4) from a per-lane descriptor quad.
__device__ inline void emit4(uint4 d, const char* __restrict__ rowXV, float* __restrict__ o) {
    vfloat4 v;
    {
        unsigned wd = d.x;
        float sf = __uint_as_float(wd & 0xFF800000u);                 // 2^deg
        float2 xv = *reinterpret_cast<const float2*>(rowXV + (wd & 0xF8u));
        float e  = __builtin_amdgcn_exp2f(xv.y * (sf * sf));          // exp(-0.5*var*4^deg)
        float ph = (float)(wd & 1u) * 0.25f;
        v.x = e * __builtin_amdgcn_sinf(__builtin_amdgcn_fractf(xv.x * sf + ph));
    }
    {
        unsigned wd = d.y;
        float sf = __uint_as_float(wd & 0xFF800000u);
        float2 xv = *reinterpret_cast<const float2*>(rowXV + (wd & 0xF8u));
        float e  = __builtin_amdgcn_exp2f(xv.y * (sf * sf));
        float ph = (float)(wd & 1u) * 0.25f;
        v.y = e * __builtin_amdgcn_sinf(__builtin_amdgcn_fractf(xv.x * sf + ph));
    }
    {
        unsigned wd = d.z;
        float sf = __uint_as_float(wd & 0xFF800000u);
        float2 xv = *reinterpret_cast<const float2*>(rowXV + (wd & 0xF8u));
        float e  = __builtin_amdgcn_exp2f(xv.y * (sf * sf));
        float ph = (float)(wd & 1u) * 0.25f;
        v.z = e * __builtin_amdgcn_sinf(__builtin_amdgcn_fractf(xv.x * sf + ph));
    }
    {
        unsigned wd = d.w;
        float sf = __uint_as_float(wd & 0xFF800000u);
        float2 xv = *reinterpret_cast<const float2*>(rowXV + (wd & 0xF8u));
        float e  = __builtin_amdgcn_exp2f(xv.y * (sf * sf));
        float ph = (float)(wd & 1u) * 0.25f;
        v.w = e * __builtin_amdgcn_sinf(__builtin_amdgcn_fractf(xv.x * sf + ph));
    }
    __builtin_nontemporal_store(v, reinterpret_cast<vfloat4*>(o));
}

// 8 blocks/CU target: VGPR<=64 cap (we use ~36), LDS 18.9KB*8 = 151.5KB <= 160KB.
__global__ __launch_bounds__(256, 8) void mipnerf_enc(
    const float* __restrict__ ray_o,
    const float* __restrict__ ray_d,
    const float* __restrict__ fgz,
    const float* __restrict__ bgz,
    const float* __restrict__ radii,
    float* __restrict__ out)
{
    const int n   = blockIdx.x;
    const int tid = threadIdx.x;

    // Per-sample sources: 24 pairs (X = x/2pi, V = -0.5*log2e * var), stride 50 floats (odd/2 pad).
    __shared__ float sXV[NS * 50];
    // Per-sample bg core: x0..2, u0..2, g, c1, c2, c3 (stride 11).
    __shared__ float sCore[NS * 11];
    // Per-channel descriptors, copied from __constant__ (16B-aligned for uint4 reads).
    __shared__ __align__(16) unsigned sD[768];

    const float ox = ray_o[3 * n + 0], oy = ray_o[3 * n + 1], oz = ray_o[3 * n + 2];
    const float dx = ray_d[3 * n + 0], dy = ray_d[3 * n + 1], dz = ray_d[3 * n + 2];
    const float rad = radii[n];
    const float dm = fmaxf(1e-8f, dx * dx + dy * dy + dz * dz);
    const float inv_dm = 1.0f / dm;

    // ---- Phase 1, split across waves so fg and bg run CONCURRENTLY ----
    if (tid < NS) {
        // threads 0..63: FG (diagonal covariance) for sample tid
        const int s = tid;
        float t0 = fgz[(NS + 1) * n + s];
        float t1 = fgz[(NS + 1) * n + s + 1];
        Moments mm = frustum_moments(t0, t1, rad);
        float d3[3] = {dx, dy, dz};
        float o3[3] = {ox, oy, oz};
        #pragma unroll
        for (int i = 0; i < 3; ++i) {
            float m  = o3[i] + d3[i] * mm.t_mean;
            float dd = d3[i] * d3[i];
            float cd = mm.t_var * dd + mm.r_var * (1.0f - dd * inv_dm);
            sXV[s * 50 + 2 * (21 + i) + 0] = m  * INV2PI;
            sXV[s * 50 + 2 * (21 + i) + 1] = cd * NEGHL2E;
        }
    } else if (tid < 2 * NS) {
        // threads 64..127: BG core (full cov + contraction) for sample tid-64
        const int s = tid - NS;
        float t0 = bgz[(NS + 1) * n + s];
        float t1 = bgz[(NS + 1) * n + s + 1];
        Moments mm = frustum_moments(t0, t1, rad);
        float x0 = ox + dx * mm.t_mean;
        float x1 = oy + dy * mm.t_mean;
        float x2 = oz + dz * mm.t_mean;
        float a  = mm.t_var - mm.r_var * inv_dm;   // C = a*ddT + rv*I
        float rv = mm.r_var;
        float rn2 = x0 * x0 + x1 * x1 + x2 * x2;
        float rn  = sqrtf(rn2);
        float nn  = rn + 1e-6f;
        float inn = 1.0f / nn;
        float g   = (2.0f * nn - 1.0f) * inn * inn;       // (2 - 1/n)/n
        float gp  = 2.0f * (1.0f - nn) * inn * inn * inn; // g'(n)
        float h   = gp / rn;                              // J = g*I + h*x*xT
        float xd  = x0 * dx + x1 * dy + x2 * dz;
        float hxd = h * xd;
        float u0 = g * dx + hxd * x0;                     // u = J d
        float u1 = g * dy + hxd * x1;
        float u2 = g * dz + hxd * x2;
        float w  = 2.0f * g * h + h * h * rn2;            // J^2 = g^2 I + w x xT
        float* cr = &sCore[s * 11];
        cr[0] = x0; cr[1] = x1; cr[2] = x2;
        cr[3] = u0; cr[4] = u1; cr[5] = u2;
        cr[6] = g;  cr[7] = a;  cr[8] = rv * g * g; cr[9] = rv * w;
    } else {
        // threads 128..255: copy channel descriptors to LDS (6 each)
        for (int e = tid - 2 * NS; e < 768; e += 128) sD[e] = cDesc.v[e];
    }
    __syncthreads();

    // ---- BG projections onto 21 basis columns (k wave-uniform, s = lane) ----
    #pragma unroll
    for (int j = 0; j < 6; ++j) {
        int i = tid + 256 * j;
        if (i < 21 * NS) {
            int k = i >> 6;        // wave-uniform
            int s = i & (NS - 1);  // = lane
            const float p0 = c_P[k], p1 = c_P[21 + k], p2 = c_P[42 + k];
            const float* cr = &sCore[s * 11];
            float x0 = cr[0], x1 = cr[1], x2 = cr[2];
            float u0 = cr[3], u1 = cr[4], u2 = cr[5];
            float g = cr[6], c1 = cr[7], c2 = cr[8], c3 = cr[9];
            float dpx = p0 * x0 + p1 * x1 + p2 * x2;
            float dpu = p0 * u0 + p1 * u1 + p2 * u2;
            float pp  = p0 * p0 + p1 * p1 + p2 * p2;
            float y   = g * dpx;
            float yv  = c1 * dpu * dpu + c2 * pp + c3 * dpx * dpx;
            sXV[s * 50 + 2 * k + 0] = y  * INV2PI;
            sXV[s * 50 + 2 * k + 1] = yv * NEGHL2E;
        }
    }
    __syncthreads();

    // ---- Emit: strictly-linear per-wave store stream (proven 5.4 TB/s). ----
    // Wave w owns samples [16w, 16w+16) = one contiguous 48 KB run.
    // Per sample row (3072 B): 3 ascending 1 KB coalesced NT stores.
    const int lane = tid & 63;
    const int w    = tid >> 6;     // wave id 0..3
    const uint4* sD4 = reinterpret_cast<const uint4*>(sD);
    const uint4 d0 = sD4[lane];        // channels   0 + lane*4 .. +3
    const uint4 d1 = sD4[64 + lane];   // channels 256 + lane*4 .. +3
    const uint4 d2 = sD4[128 + lane];  // channels 512 + lane*4 .. +3

    float* __restrict__ outp = out + (size_t)n * (NS * 768);

    for (int ss = 0; ss < 16; ++ss) {
        const int s = w * 16 + ss;
        const char* rowXV = reinterpret_cast<const char*>(&sXV[s * 50]);
        float* orow = outp + s * 768 + lane * 4;
        emit4(d0, rowXV, orow);
        emit4(d1, rowXV, orow + 256);
        emit4(d2, rowXV, orow + 512);
    }
}

extern "C" void kernel_launch(void* const* d_in, const int* in_sizes, int n_in,
                              void* d_out, int out_size, void* d_ws, size_t ws_size,
                              hipStream_t stream) {
    const float* ray_o = (const float*)d_in[0];
    const float* ray_d = (const float*)d_in[1];
    const float* fgz   = (const float*)d_in[2];
    const float* bgz   = (const float*)d_in[3];
    const float* radii = (const float*)d_in[4];
    float* out = (float*)d_out;
    const int N = in_sizes[0] / 3;   // 2048 rays
    mipnerf_enc<<<N, 256, 0, stream>>>(ray_o, ray_d, fgz, bgz, radii, out);
}